// Round 1
// baseline (563.506 us; speedup 1.0000x reference)
//
#include <hip/hip_runtime.h>
#include <math.h>

// FATM spiking token mixer, MI355X baseline (round 1).
// Shapes: T=4 B=8 C=512 H=W=32, nb=16 bs=32.
// Workspace layout (needs 33,558,528 B):
//   [0, 4096)                : Q (32x32 f32 Haar matrix, built on device)
//   [4096, +16777216)        : xs  spikes of LIF(x), u8, [T,B,C,H,W]
//   [.., +16777216)          : h1  spikes after Haar-fwd/NegIF/BN0/LIF, u8
// d_out doubles as the "mixed" buffer between k_mix and k_haar_inv.

#define T_    4
#define B_    8
#define C_    512
#define HW_   1024
#define CHW_  524288      // C_*HW_
#define BCHW_ 4194304     // B_*CHW_
#define NB_   16
#define EPS_  1e-5f
#define QSTR  36          // LDS row stride (floats) for 32-row tiles: 144B, 16B-aligned

// ---------------------------------------------------------------- Q builder
// Replicates the numpy construction: entries are (1/sqrt(2))^(5-p) computed by
// repeated double division, rounded once to f32 (bit-matches np->f32 path).
__global__ void k_build_q(float* __restrict__ q) {
  int idx = threadIdx.x;            // 1024 threads
  int k = idx >> 5, j = idx & 31;
  double m = 1.0;
  if (k == 0) {
    for (int s = 0; s < 5; ++s) m /= sqrt(2.0);
    q[idx] = (float)m;
    return;
  }
  int p = 31 - __clz(k);            // floor(log2 k)
  for (int s = 0; s < 5 - p; ++s) m /= sqrt(2.0);
  int L = 32 >> p;
  int st = (k - (1 << p)) * L;
  int half = L >> 1;
  float v = 0.0f;
  if (j >= st && j < st + half)       v = (float)m;
  else if (j >= st + half && j < st + L) v = -(float)m;
  q[idx] = v;
}

// ---------------------------------------------------------------- LIF on x
// v += (x - v)*0.5 ; s = v>=1 ; v = s?0:v   (bit-exact vs reference: *0.5 exact)
__global__ __launch_bounds__(256) void k_lif_x(const float* __restrict__ x,
                                               unsigned char* __restrict__ xs) {
  size_t i4 = ((size_t)blockIdx.x * 256 + threadIdx.x) * 4;   // grid 4096
  float v[4] = {0.f, 0.f, 0.f, 0.f};
  for (int t = 0; t < T_; ++t) {
    float4 xv = *(const float4*)(x + (size_t)t * BCHW_ + i4);
    float xa[4] = {xv.x, xv.y, xv.z, xv.w};
    unsigned char sb[4];
#pragma unroll
    for (int e = 0; e < 4; ++e) {
      v[e] += (xa[e] - v[e]) * 0.5f;
      bool sp = v[e] >= 1.0f;
      sb[e] = sp ? 1 : 0;
      if (sp) v[e] = 0.0f;
    }
    uchar4 s; s.x = sb[0]; s.y = sb[1]; s.z = sb[2]; s.w = sb[3];
    *(uchar4*)(xs + (size_t)t * BCHW_ + i4) = s;
  }
}

// ------------------------------------------- Haar fwd + NegIF + BN0 + LIF
// Per (b,c) image, loop t with NegIF/LIF state in registers.
// 4 images per 256-thread block; each thread computes a 4x4 output tile.
__global__ __launch_bounds__(256) void k_haar_fwd(
    const unsigned char* __restrict__ xs, const float* __restrict__ qg,
    const float* __restrict__ bnw, const float* __restrict__ bnb,
    const float* __restrict__ bnm, const float* __restrict__ bnv,
    unsigned char* __restrict__ h1) {
  __shared__ __align__(16) float QT[32 * QSTR];      // QT[j][i] = Q[i][j]
  __shared__ __align__(16) float Xs[4][32 * QSTR];
  __shared__ __align__(16) float Tt[4][32 * QSTR];   // Tt[k][i] = tmp[i][k]
  const int tid = threadIdx.x;
  for (int e2 = tid; e2 < 1024; e2 += 256) {
    int i = e2 >> 5, j = e2 & 31;
    QT[j * QSTR + i] = qg[e2];
  }
  const int im = tid >> 6;
  const int e  = tid & 63;
  const int i0 = (e >> 3) * 4;
  const int c0 = (e & 7) * 4;
  const int gc = blockIdx.x * 4 + im;      // b*512 + c
  const int c  = gc & 511;
  const float inv0 = bnw[c] / sqrtf(bnv[c] + EPS_);
  const float bet0 = __fsub_rn(bnb[c], __fmul_rn(bnm[c], inv0));
  const size_t base = (size_t)(gc >> 9) * CHW_ + (size_t)c * HW_;
  float vn[4][4], vl[4][4];
#pragma unroll
  for (int r = 0; r < 4; ++r)
#pragma unroll
    for (int q = 0; q < 4; ++q) { vn[r][q] = 0.f; vl[r][q] = 0.f; }
  __syncthreads();
  for (int t = 0; t < T_; ++t) {
    // stage spikes -> f32 in LDS
    const uchar4* sp = (const uchar4*)(xs + (size_t)t * BCHW_ + base + e * 16);
#pragma unroll
    for (int q = 0; q < 4; ++q) {
      uchar4 s4 = sp[q];
      int px = e * 16 + q * 4;
      float4 f;
      f.x = (float)s4.x; f.y = (float)s4.y; f.z = (float)s4.z; f.w = (float)s4.w;
      *(float4*)&Xs[im][(px >> 5) * QSTR + (px & 31)] = f;
    }
    __syncthreads();
    // phase1: tmp[i,k] = sum_j Q[i,j]*X[j,k]   (Q[i,j] = QT[j][i])
    float a[4][4];
#pragma unroll
    for (int r = 0; r < 4; ++r)
#pragma unroll
      for (int q = 0; q < 4; ++q) a[r][q] = 0.f;
    for (int j = 0; j < 32; ++j) {
      float4 qv = *(const float4*)&QT[j * QSTR + i0];
      float4 xv = *(const float4*)&Xs[im][j * QSTR + c0];
      float qa[4] = {qv.x, qv.y, qv.z, qv.w};
      float xa[4] = {xv.x, xv.y, xv.z, xv.w};
#pragma unroll
      for (int r = 0; r < 4; ++r)
#pragma unroll
        for (int q = 0; q < 4; ++q) a[r][q] = fmaf(qa[r], xa[q], a[r][q]);
    }
#pragma unroll
    for (int q = 0; q < 4; ++q) {
      float4 f; f.x = a[0][q]; f.y = a[1][q]; f.z = a[2][q]; f.w = a[3][q];
      *(float4*)&Tt[im][(c0 + q) * QSTR + i0] = f;
    }
    __syncthreads();
    // phase2: Y[i,l] = sum_k tmp[i,k]*Q[l,k]  (tmp[i,k]=Tt[k][i], Q[l,k]=QT[k][l])
    float y[4][4];
#pragma unroll
    for (int r = 0; r < 4; ++r)
#pragma unroll
      for (int q = 0; q < 4; ++q) y[r][q] = 0.f;
    for (int k = 0; k < 32; ++k) {
      float4 tv = *(const float4*)&Tt[im][k * QSTR + i0];
      float4 qv = *(const float4*)&QT[k * QSTR + c0];
      float ta[4] = {tv.x, tv.y, tv.z, tv.w};
      float qa[4] = {qv.x, qv.y, qv.z, qv.w};
#pragma unroll
      for (int r = 0; r < 4; ++r)
#pragma unroll
        for (int q = 0; q < 4; ++q) y[r][q] = fmaf(ta[r], qa[q], y[r][q]);
    }
    // NegIF -> BN0 -> LIF (rounding forced to match XLA's separate mul/add)
#pragma unroll
    for (int r = 0; r < 4; ++r) {
      unsigned char sb[4];
#pragma unroll
      for (int q = 0; q < 4; ++q) {
        vn[r][q] += y[r][q];
        float s = 0.f;
        if (vn[r][q] >= 1.0f) s = 1.0f;
        else if (vn[r][q] <= -1.0f) s = -1.0f;
        vn[r][q] -= s;
        float bv = __fadd_rn(__fmul_rn(s, inv0), bet0);
        vl[r][q] += (bv - vl[r][q]) * 0.5f;
        bool spk = vl[r][q] >= 1.0f;
        sb[q] = spk ? 1 : 0;
        if (spk) vl[r][q] = 0.f;
      }
      uchar4 so; so.x = sb[0]; so.y = sb[1]; so.z = sb[2]; so.w = sb[3];
      *(uchar4*)(h1 + (size_t)t * BCHW_ + base + (size_t)((i0 + r) * 32 + c0)) = so;
    }
  }
}

// ---------------------------------------- block-diag channel mix + BN1
// out[n, blk*32+k, p] = BN1( sum_d h1[n, blk*32+d, p] * W[blk,d,k] ), into d_out.
__global__ __launch_bounds__(256) void k_mix(
    const unsigned char* __restrict__ h1, const float* __restrict__ hwt,
    const float* __restrict__ bnw, const float* __restrict__ bnb,
    const float* __restrict__ bnm, const float* __restrict__ bnv,
    float* __restrict__ outm) {
  __shared__ unsigned char S[32 * 1024];
  __shared__ float Wt[1024];
  const int n = blockIdx.x;       // T*B
  const int blk = blockIdx.y;     // nb
  const int tid = threadIdx.x;
  for (int e = tid; e < 1024; e += 256) Wt[e] = hwt[blk * 1024 + e];
  const uint4* src = (const uint4*)(h1 + (size_t)n * CHW_ + (size_t)blk * 32 * HW_);
  uint4* dst = (uint4*)S;
  for (int e = tid; e < 2048; e += 256) dst[e] = src[e];
  __syncthreads();
  const int p0 = tid * 4;
  for (int k = 0; k < 32; ++k) {
    const int c = blk * 32 + k;
    const float inv = bnw[C_ + c] / sqrtf(bnv[C_ + c] + EPS_);
    const float bet = __fsub_rn(bnb[C_ + c], __fmul_rn(bnm[C_ + c], inv));
    float a0 = 0.f, a1 = 0.f, a2 = 0.f, a3 = 0.f;
    for (int d = 0; d < 32; ++d) {
      const float w = Wt[d * 32 + k];                       // broadcast
      const unsigned int sp = *(const unsigned int*)(S + d * 1024 + p0);
      a0 = fmaf((float)(sp & 255u), w, a0);
      a1 = fmaf((float)((sp >> 8) & 255u), w, a1);
      a2 = fmaf((float)((sp >> 16) & 255u), w, a2);
      a3 = fmaf((float)((sp >> 24) & 255u), w, a3);
    }
    float4 o;
    o.x = __fadd_rn(__fmul_rn(a0, inv), bet);
    o.y = __fadd_rn(__fmul_rn(a1, inv), bet);
    o.z = __fadd_rn(__fmul_rn(a2, inv), bet);
    o.w = __fadd_rn(__fmul_rn(a3, inv), bet);
    *(float4*)(outm + (size_t)n * CHW_ + (size_t)c * HW_ + p0) = o;
  }
}

// ------------------------------------------- Haar inverse + NegIF + BN2
// In-place on d_out (reads "mixed", writes haar-branch contribution).
__global__ __launch_bounds__(256) void k_haar_inv(
    const float* __restrict__ qg,
    const float* __restrict__ bnw, const float* __restrict__ bnb,
    const float* __restrict__ bnm, const float* __restrict__ bnv,
    float* out) {
  __shared__ __align__(16) float Qn[32 * QSTR];      // row-major Q
  __shared__ __align__(16) float Xs[4][32 * QSTR];
  __shared__ __align__(16) float Tt[4][32 * QSTR];
  const int tid = threadIdx.x;
  for (int e2 = tid; e2 < 1024; e2 += 256) {
    int i = e2 >> 5, j = e2 & 31;
    Qn[i * QSTR + j] = qg[e2];
  }
  const int im = tid >> 6;
  const int e  = tid & 63;
  const int i0 = (e >> 3) * 4;
  const int c0 = (e & 7) * 4;
  const int gc = blockIdx.x * 4 + im;
  const int c  = gc & 511;
  const float inv2 = bnw[2 * C_ + c] / sqrtf(bnv[2 * C_ + c] + EPS_);
  const float bet2 = __fsub_rn(bnb[2 * C_ + c], __fmul_rn(bnm[2 * C_ + c], inv2));
  const size_t base = (size_t)(gc >> 9) * CHW_ + (size_t)c * HW_;
  float vn[4][4];
#pragma unroll
  for (int r = 0; r < 4; ++r)
#pragma unroll
    for (int q = 0; q < 4; ++q) vn[r][q] = 0.f;
  __syncthreads();
  for (int t = 0; t < T_; ++t) {
    const float4* sp = (const float4*)(out + (size_t)t * BCHW_ + base + e * 16);
#pragma unroll
    for (int q = 0; q < 4; ++q) {
      float4 f = sp[q];
      int px = e * 16 + q * 4;
      *(float4*)&Xs[im][(px >> 5) * QSTR + (px & 31)] = f;
    }
    __syncthreads();
    // phase1: tmp[i,k] = sum_j Q[j,i]*X[j,k]
    float a[4][4];
#pragma unroll
    for (int r = 0; r < 4; ++r)
#pragma unroll
      for (int q = 0; q < 4; ++q) a[r][q] = 0.f;
    for (int j = 0; j < 32; ++j) {
      float4 qv = *(const float4*)&Qn[j * QSTR + i0];     // Q[j][i0..3]
      float4 xv = *(const float4*)&Xs[im][j * QSTR + c0];
      float qa[4] = {qv.x, qv.y, qv.z, qv.w};
      float xa[4] = {xv.x, xv.y, xv.z, xv.w};
#pragma unroll
      for (int r = 0; r < 4; ++r)
#pragma unroll
        for (int q = 0; q < 4; ++q) a[r][q] = fmaf(qa[r], xa[q], a[r][q]);
    }
#pragma unroll
    for (int q = 0; q < 4; ++q) {
      float4 f; f.x = a[0][q]; f.y = a[1][q]; f.z = a[2][q]; f.w = a[3][q];
      *(float4*)&Tt[im][(c0 + q) * QSTR + i0] = f;
    }
    __syncthreads();
    // phase2: Y[i,l] = sum_k tmp[i,k]*Q[k,l]
    float y[4][4];
#pragma unroll
    for (int r = 0; r < 4; ++r)
#pragma unroll
      for (int q = 0; q < 4; ++q) y[r][q] = 0.f;
    for (int k = 0; k < 32; ++k) {
      float4 tv = *(const float4*)&Tt[im][k * QSTR + i0];
      float4 qv = *(const float4*)&Qn[k * QSTR + c0];     // Q[k][c0..3]
      float ta[4] = {tv.x, tv.y, tv.z, tv.w};
      float qa[4] = {qv.x, qv.y, qv.z, qv.w};
#pragma unroll
      for (int r = 0; r < 4; ++r)
#pragma unroll
        for (int q = 0; q < 4; ++q) y[r][q] = fmaf(ta[r], qa[q], y[r][q]);
    }
#pragma unroll
    for (int r = 0; r < 4; ++r) {
      float res[4];
#pragma unroll
      for (int q = 0; q < 4; ++q) {
        vn[r][q] += y[r][q];
        float s = 0.f;
        if (vn[r][q] >= 1.0f) s = 1.0f;
        else if (vn[r][q] <= -1.0f) s = -1.0f;
        vn[r][q] -= s;
        res[q] = __fadd_rn(__fmul_rn(s, inv2), bet2);
      }
      float4 ov; ov.x = res[0]; ov.y = res[1]; ov.z = res[2]; ov.w = res[3];
      *(float4*)(out + (size_t)t * BCHW_ + base + (size_t)((i0 + r) * 32 + c0)) = ov;
    }
  }
}

// ---------------------- conv branch (1x1 + 3x3 grouped) + BN3/BN4 + final add
// out = haar(out) + BN3(conv1(xs)+b1) + BN4(conv2(xs)+b2) + x
#define SPAD_ 39176   // 4 guard + 32*34*36 padded u8 spike tile
__global__ __launch_bounds__(256) void k_conv(
    const unsigned char* __restrict__ xs, const float* __restrict__ x,
    const float* __restrict__ w1, const float* __restrict__ b1,
    const float* __restrict__ w2, const float* __restrict__ b2,
    const float* __restrict__ bnw, const float* __restrict__ bnb,
    const float* __restrict__ bnm, const float* __restrict__ bnv,
    float* out) {
  __shared__ __align__(16) unsigned char S[SPAD_];
  const int n = blockIdx.x;      // T*B
  const int blk = blockIdx.y;    // nb
  const int tid = threadIdx.x;
  for (int e = tid; e < SPAD_ / 4; e += 256) ((unsigned int*)S)[e] = 0u;
  __syncthreads();
  // interior: input (ic, yy, xx) -> S[4 + ic*1224 + (yy+1)*36 + xx]
  for (int r = tid; r < 1024; r += 256) {
    int ic = r >> 5, yy = r & 31;
    const unsigned int* srcw =
        (const unsigned int*)(xs + (size_t)n * CHW_ + (size_t)(blk * 32 + ic) * HW_ + yy * 32);
    unsigned int* dw = (unsigned int*)&S[4 + ic * 1224 + (yy + 1) * 36];
#pragma unroll
    for (int w8 = 0; w8 < 8; ++w8) dw[w8] = srcw[w8];
  }
  __syncthreads();
  const int y = tid >> 3;
  const int x0 = (tid & 7) * 4;
  for (int ob = blockIdx.z * 2; ob < blockIdx.z * 2 + 2; ++ob) {
    float acc2[8][4], acc1[8][4];
#pragma unroll
    for (int o = 0; o < 8; ++o)
#pragma unroll
      for (int e = 0; e < 4; ++e) { acc2[o][e] = 0.f; acc1[o][e] = 0.f; }
    for (int ic = 0; ic < 32; ++ic) {
      float win[3][6];
      const unsigned char* sp = &S[4 + ic * 1224 + y * 36 + x0 - 1];
#pragma unroll
      for (int r = 0; r < 3; ++r)
#pragma unroll
        for (int q2 = 0; q2 < 6; ++q2) win[r][q2] = (float)sp[r * 36 + q2];
#pragma unroll
      for (int o = 0; o < 8; ++o) {
        const int oc = ob * 8 + o;
        const float* wp = &w2[(oc * 32 + ic) * 9];
        const float wc = w1[oc * 32 + ic];
        const float w00 = wp[0], w01 = wp[1], w02 = wp[2];
        const float w10 = wp[3], w11 = wp[4], w12 = wp[5];
        const float w20 = wp[6], w21 = wp[7], w22 = wp[8];
#pragma unroll
        for (int e = 0; e < 4; ++e) {
          float a = acc2[o][e];
          a = fmaf(win[0][e + 0], w00, a);
          a = fmaf(win[0][e + 1], w01, a);
          a = fmaf(win[0][e + 2], w02, a);
          a = fmaf(win[1][e + 0], w10, a);
          a = fmaf(win[1][e + 1], w11, a);
          a = fmaf(win[1][e + 2], w12, a);
          a = fmaf(win[2][e + 0], w20, a);
          a = fmaf(win[2][e + 1], w21, a);
          a = fmaf(win[2][e + 2], w22, a);
          acc2[o][e] = a;
          acc1[o][e] = fmaf(win[1][e + 1], wc, acc1[o][e]);
        }
      }
    }
#pragma unroll
    for (int o = 0; o < 8; ++o) {
      const int oc = ob * 8 + o;
      const int c = blk * 32 + oc;
      const float inv3 = bnw[3 * C_ + c] / sqrtf(bnv[3 * C_ + c] + EPS_);
      const float bet3 = __fsub_rn(bnb[3 * C_ + c], __fmul_rn(bnm[3 * C_ + c], inv3));
      const float inv4 = bnw[4 * C_ + c] / sqrtf(bnv[4 * C_ + c] + EPS_);
      const float bet4 = __fsub_rn(bnb[4 * C_ + c], __fmul_rn(bnm[4 * C_ + c], inv4));
      const float bb1 = b1[oc], bb2 = b2[oc];
      const size_t off = (size_t)n * CHW_ + (size_t)c * HW_ + (size_t)(y * 32 + x0);
      const float4 hv = *(const float4*)(out + off);
      const float4 xv = *(const float4*)(x + off);
      const float hva[4] = {hv.x, hv.y, hv.z, hv.w};
      const float xva[4] = {xv.x, xv.y, xv.z, xv.w};
      float res[4];
#pragma unroll
      for (int e = 0; e < 4; ++e) {
        float c1v = __fadd_rn(acc1[o][e], bb1);
        float c2v = __fadd_rn(acc2[o][e], bb2);
        float t1 = __fadd_rn(hva[e], __fadd_rn(__fmul_rn(c1v, inv3), bet3));
        float t2 = __fadd_rn(t1, __fadd_rn(__fmul_rn(c2v, inv4), bet4));
        res[e] = __fadd_rn(t2, xva[e]);
      }
      float4 ov; ov.x = res[0]; ov.y = res[1]; ov.z = res[2]; ov.w = res[3];
      *(float4*)(out + off) = ov;
    }
  }
}

extern "C" void kernel_launch(void* const* d_in, const int* in_sizes, int n_in,
                              void* d_out, int out_size, void* d_ws, size_t ws_size,
                              hipStream_t stream) {
  (void)in_sizes; (void)n_in; (void)out_size; (void)ws_size;
  const float* x   = (const float*)d_in[0];
  const float* hwt = (const float*)d_in[1];
  const float* w1  = (const float*)d_in[2];
  const float* b1  = (const float*)d_in[3];
  const float* w2  = (const float*)d_in[4];
  const float* b2  = (const float*)d_in[5];
  const float* bnw = (const float*)d_in[6];
  const float* bnb = (const float*)d_in[7];
  const float* bnm = (const float*)d_in[8];
  const float* bnv = (const float*)d_in[9];
  float* out = (float*)d_out;

  float* qg = (float*)d_ws;
  unsigned char* xs = (unsigned char*)d_ws + 4096;
  unsigned char* h1 = xs + (size_t)T_ * BCHW_;

  k_build_q<<<1, 1024, 0, stream>>>(qg);
  k_lif_x<<<BCHW_ / 1024, 256, 0, stream>>>(x, xs);
  k_haar_fwd<<<(B_ * C_) / 4, 256, 0, stream>>>(xs, qg, bnw, bnb, bnm, bnv, h1);
  k_mix<<<dim3(T_ * B_, NB_), 256, 0, stream>>>(h1, hwt, bnw, bnb, bnm, bnv, out);
  k_haar_inv<<<(B_ * C_) / 4, 256, 0, stream>>>(qg, bnw, bnb, bnm, bnv, out);
  k_conv<<<dim3(T_ * B_, NB_, 2), 256, 0, stream>>>(xs, x, w1, b1, w2, b2,
                                                    bnw, bnb, bnm, bnv, out);
}

// Round 5
// 399.379 us; speedup vs baseline: 1.4110x; 1.4110x over previous
//
#include <hip/hip_runtime.h>
#include <math.h>

// FATM spiking token mixer, MI355X (round 2 resubmit #3: MFMA conv branch).
// Shapes: T=4 B=8 C=512 H=W=32, nb=16 bs=32.
// Workspace layout (33,558,528 B, unchanged from round 1):
//   [0, 4096)            : Q (32x32 f32 Haar matrix, built on device)
//   [4096, +16777216)    : xs  spikes of LIF(x), u8, [T,B,C,H,W]
//   [.., +16777216)      : h1  spikes after Haar-fwd/NegIF/BN0/LIF, u8
// d_out doubles as the "mixed"/haar buffer between k_mix and k_conv_mfma.

#define T_    4
#define B_    8
#define C_    512
#define HW_   1024
#define CHW_  524288      // C_*HW_
#define BCHW_ 4194304     // B_*CHW_
#define NB_   16
#define EPS_  1e-5f
#define QSTR  36          // LDS row stride (floats) for 32-row f32 tiles

typedef _Float16 half8_t __attribute__((ext_vector_type(8)));
typedef float f32x16_t __attribute__((ext_vector_type(16)));

// ---------------------------------------------------------------- Q builder
__global__ void k_build_q(float* __restrict__ q) {
  int idx = threadIdx.x;            // 1024 threads
  int k = idx >> 5, j = idx & 31;
  double m = 1.0;
  if (k == 0) {
    for (int s = 0; s < 5; ++s) m /= sqrt(2.0);
    q[idx] = (float)m;
    return;
  }
  int p = 31 - __clz(k);            // floor(log2 k)
  for (int s = 0; s < 5 - p; ++s) m /= sqrt(2.0);
  int L = 32 >> p;
  int st = (k - (1 << p)) * L;
  int half = L >> 1;
  float v = 0.0f;
  if (j >= st && j < st + half)       v = (float)m;
  else if (j >= st + half && j < st + L) v = -(float)m;
  q[idx] = v;
}

// ---------------------------------------------------------------- LIF on x
__global__ __launch_bounds__(256) void k_lif_x(const float* __restrict__ x,
                                               unsigned char* __restrict__ xs) {
  size_t i4 = ((size_t)blockIdx.x * 256 + threadIdx.x) * 4;   // grid 4096
  float v[4] = {0.f, 0.f, 0.f, 0.f};
  for (int t = 0; t < T_; ++t) {
    float4 xv = *(const float4*)(x + (size_t)t * BCHW_ + i4);
    float xa[4] = {xv.x, xv.y, xv.z, xv.w};
    unsigned char sb[4];
#pragma unroll
    for (int e = 0; e < 4; ++e) {
      v[e] += (xa[e] - v[e]) * 0.5f;
      bool sp = v[e] >= 1.0f;
      sb[e] = sp ? 1 : 0;
      if (sp) v[e] = 0.0f;
    }
    uchar4 s; s.x = sb[0]; s.y = sb[1]; s.z = sb[2]; s.w = sb[3];
    *(uchar4*)(xs + (size_t)t * BCHW_ + i4) = s;
  }
}

// ------------------------------------------- Haar fwd + NegIF + BN0 + LIF
__global__ __launch_bounds__(256) void k_haar_fwd(
    const unsigned char* __restrict__ xs, const float* __restrict__ qg,
    const float* __restrict__ bnw, const float* __restrict__ bnb,
    const float* __restrict__ bnm, const float* __restrict__ bnv,
    unsigned char* __restrict__ h1) {
  __shared__ __align__(16) float QT[32 * QSTR];      // QT[j][i] = Q[i][j]
  __shared__ __align__(16) float Xs[4][32 * QSTR];
  __shared__ __align__(16) float Tt[4][32 * QSTR];   // Tt[k][i] = tmp[i][k]
  const int tid = threadIdx.x;
  for (int e2 = tid; e2 < 1024; e2 += 256) {
    int i = e2 >> 5, j = e2 & 31;
    QT[j * QSTR + i] = qg[e2];
  }
  const int im = tid >> 6;
  const int e  = tid & 63;
  const int i0 = (e >> 3) * 4;
  const int c0 = (e & 7) * 4;
  const int gc = blockIdx.x * 4 + im;      // b*512 + c
  const int c  = gc & 511;
  const float inv0 = bnw[c] / sqrtf(bnv[c] + EPS_);
  const float bet0 = __fsub_rn(bnb[c], __fmul_rn(bnm[c], inv0));
  const size_t base = (size_t)(gc >> 9) * CHW_ + (size_t)c * HW_;
  float vn[4][4], vl[4][4];
#pragma unroll
  for (int r = 0; r < 4; ++r)
#pragma unroll
    for (int q = 0; q < 4; ++q) { vn[r][q] = 0.f; vl[r][q] = 0.f; }
  __syncthreads();
  for (int t = 0; t < T_; ++t) {
    const uchar4* sp = (const uchar4*)(xs + (size_t)t * BCHW_ + base + e * 16);
#pragma unroll
    for (int q = 0; q < 4; ++q) {
      uchar4 s4 = sp[q];
      int px = e * 16 + q * 4;
      float4 f;
      f.x = (float)s4.x; f.y = (float)s4.y; f.z = (float)s4.z; f.w = (float)s4.w;
      *(float4*)&Xs[im][(px >> 5) * QSTR + (px & 31)] = f;
    }
    __syncthreads();
    float a[4][4];
#pragma unroll
    for (int r = 0; r < 4; ++r)
#pragma unroll
      for (int q = 0; q < 4; ++q) a[r][q] = 0.f;
    for (int j = 0; j < 32; ++j) {
      float4 qv = *(const float4*)&QT[j * QSTR + i0];
      float4 xv = *(const float4*)&Xs[im][j * QSTR + c0];
      float qa[4] = {qv.x, qv.y, qv.z, qv.w};
      float xa[4] = {xv.x, xv.y, xv.z, xv.w};
#pragma unroll
      for (int r = 0; r < 4; ++r)
#pragma unroll
        for (int q = 0; q < 4; ++q) a[r][q] = fmaf(qa[r], xa[q], a[r][q]);
    }
#pragma unroll
    for (int q = 0; q < 4; ++q) {
      float4 f; f.x = a[0][q]; f.y = a[1][q]; f.z = a[2][q]; f.w = a[3][q];
      *(float4*)&Tt[im][(c0 + q) * QSTR + i0] = f;
    }
    __syncthreads();
    float y[4][4];
#pragma unroll
    for (int r = 0; r < 4; ++r)
#pragma unroll
      for (int q = 0; q < 4; ++q) y[r][q] = 0.f;
    for (int k = 0; k < 32; ++k) {
      float4 tv = *(const float4*)&Tt[im][k * QSTR + i0];
      float4 qv = *(const float4*)&QT[k * QSTR + c0];
      float ta[4] = {tv.x, tv.y, tv.z, tv.w};
      float qa[4] = {qv.x, qv.y, qv.z, qv.w};
#pragma unroll
      for (int r = 0; r < 4; ++r)
#pragma unroll
        for (int q = 0; q < 4; ++q) y[r][q] = fmaf(ta[r], qa[q], y[r][q]);
    }
#pragma unroll
    for (int r = 0; r < 4; ++r) {
      unsigned char sb[4];
#pragma unroll
      for (int q = 0; q < 4; ++q) {
        vn[r][q] += y[r][q];
        float s = 0.f;
        if (vn[r][q] >= 1.0f) s = 1.0f;
        else if (vn[r][q] <= -1.0f) s = -1.0f;
        vn[r][q] -= s;
        float bv = __fadd_rn(__fmul_rn(s, inv0), bet0);
        vl[r][q] += (bv - vl[r][q]) * 0.5f;
        bool spk = vl[r][q] >= 1.0f;
        sb[q] = spk ? 1 : 0;
        if (spk) vl[r][q] = 0.f;
      }
      uchar4 so; so.x = sb[0]; so.y = sb[1]; so.z = sb[2]; so.w = sb[3];
      *(uchar4*)(h1 + (size_t)t * BCHW_ + base + (size_t)((i0 + r) * 32 + c0)) = so;
    }
  }
}

// ---------------------------------------- block-diag channel mix + BN1
__global__ __launch_bounds__(256) void k_mix(
    const unsigned char* __restrict__ h1, const float* __restrict__ hwt,
    const float* __restrict__ bnw, const float* __restrict__ bnb,
    const float* __restrict__ bnm, const float* __restrict__ bnv,
    float* __restrict__ outm) {
  __shared__ unsigned char S[32 * 1024];
  __shared__ float Wt[1024];
  const int n = blockIdx.x;       // T*B
  const int blk = blockIdx.y;     // nb
  const int tid = threadIdx.x;
  for (int e = tid; e < 1024; e += 256) Wt[e] = hwt[blk * 1024 + e];
  const uint4* src = (const uint4*)(h1 + (size_t)n * CHW_ + (size_t)blk * 32 * HW_);
  uint4* dst = (uint4*)S;
  for (int e = tid; e < 2048; e += 256) dst[e] = src[e];
  __syncthreads();
  const int p0 = tid * 4;
  for (int k = 0; k < 32; ++k) {
    const int c = blk * 32 + k;
    const float inv = bnw[C_ + c] / sqrtf(bnv[C_ + c] + EPS_);
    const float bet = __fsub_rn(bnb[C_ + c], __fmul_rn(bnm[C_ + c], inv));
    float a0 = 0.f, a1 = 0.f, a2 = 0.f, a3 = 0.f;
    for (int d = 0; d < 32; ++d) {
      const float w = Wt[d * 32 + k];                       // broadcast
      const unsigned int sp = *(const unsigned int*)(S + d * 1024 + p0);
      a0 = fmaf((float)(sp & 255u), w, a0);
      a1 = fmaf((float)((sp >> 8) & 255u), w, a1);
      a2 = fmaf((float)((sp >> 16) & 255u), w, a2);
      a3 = fmaf((float)((sp >> 24) & 255u), w, a3);
    }
    float4 o;
    o.x = __fadd_rn(__fmul_rn(a0, inv), bet);
    o.y = __fadd_rn(__fmul_rn(a1, inv), bet);
    o.z = __fadd_rn(__fmul_rn(a2, inv), bet);
    o.w = __fadd_rn(__fmul_rn(a3, inv), bet);
    *(float4*)(outm + (size_t)n * CHW_ + (size_t)c * HW_ + p0) = o;
  }
}

// ------------------------------------------- Haar inverse + NegIF + BN2
__global__ __launch_bounds__(256) void k_haar_inv(
    const float* __restrict__ qg,
    const float* __restrict__ bnw, const float* __restrict__ bnb,
    const float* __restrict__ bnm, const float* __restrict__ bnv,
    float* out) {
  __shared__ __align__(16) float Qn[32 * QSTR];      // row-major Q
  __shared__ __align__(16) float Xs[4][32 * QSTR];
  __shared__ __align__(16) float Tt[4][32 * QSTR];
  const int tid = threadIdx.x;
  for (int e2 = tid; e2 < 1024; e2 += 256) {
    int i = e2 >> 5, j = e2 & 31;
    Qn[i * QSTR + j] = qg[e2];
  }
  const int im = tid >> 6;
  const int e  = tid & 63;
  const int i0 = (e >> 3) * 4;
  const int c0 = (e & 7) * 4;
  const int gc = blockIdx.x * 4 + im;
  const int c  = gc & 511;
  const float inv2 = bnw[2 * C_ + c] / sqrtf(bnv[2 * C_ + c] + EPS_);
  const float bet2 = __fsub_rn(bnb[2 * C_ + c], __fmul_rn(bnm[2 * C_ + c], inv2));
  const size_t base = (size_t)(gc >> 9) * CHW_ + (size_t)c * HW_;
  float vn[4][4];
#pragma unroll
  for (int r = 0; r < 4; ++r)
#pragma unroll
    for (int q = 0; q < 4; ++q) vn[r][q] = 0.f;
  __syncthreads();
  for (int t = 0; t < T_; ++t) {
    const float4* sp = (const float4*)(out + (size_t)t * BCHW_ + base + e * 16);
#pragma unroll
    for (int q = 0; q < 4; ++q) {
      float4 f = sp[q];
      int px = e * 16 + q * 4;
      *(float4*)&Xs[im][(px >> 5) * QSTR + (px & 31)] = f;
    }
    __syncthreads();
    float a[4][4];
#pragma unroll
    for (int r = 0; r < 4; ++r)
#pragma unroll
      for (int q = 0; q < 4; ++q) a[r][q] = 0.f;
    for (int j = 0; j < 32; ++j) {
      float4 qv = *(const float4*)&Qn[j * QSTR + i0];     // Q[j][i0..3]
      float4 xv = *(const float4*)&Xs[im][j * QSTR + c0];
      float qa[4] = {qv.x, qv.y, qv.z, qv.w};
      float xa[4] = {xv.x, xv.y, xv.z, xv.w};
#pragma unroll
      for (int r = 0; r < 4; ++r)
#pragma unroll
        for (int q = 0; q < 4; ++q) a[r][q] = fmaf(qa[r], xa[q], a[r][q]);
    }
#pragma unroll
    for (int q = 0; q < 4; ++q) {
      float4 f; f.x = a[0][q]; f.y = a[1][q]; f.z = a[2][q]; f.w = a[3][q];
      *(float4*)&Tt[im][(c0 + q) * QSTR + i0] = f;
    }
    __syncthreads();
    float y[4][4];
#pragma unroll
    for (int r = 0; r < 4; ++r)
#pragma unroll
      for (int q = 0; q < 4; ++q) y[r][q] = 0.f;
    for (int k = 0; k < 32; ++k) {
      float4 tv = *(const float4*)&Tt[im][k * QSTR + i0];
      float4 qv = *(const float4*)&Qn[k * QSTR + c0];     // Q[k][c0..3]
      float ta[4] = {tv.x, tv.y, tv.z, tv.w};
      float qa[4] = {qv.x, qv.y, qv.z, qv.w};
#pragma unroll
      for (int r = 0; r < 4; ++r)
#pragma unroll
        for (int q = 0; q < 4; ++q) y[r][q] = fmaf(ta[r], qa[q], y[r][q]);
    }
#pragma unroll
    for (int r = 0; r < 4; ++r) {
      float res[4];
#pragma unroll
      for (int q = 0; q < 4; ++q) {
        vn[r][q] += y[r][q];
        float s = 0.f;
        if (vn[r][q] >= 1.0f) s = 1.0f;
        else if (vn[r][q] <= -1.0f) s = -1.0f;
        vn[r][q] -= s;
        res[q] = __fadd_rn(__fmul_rn(s, inv2), bet2);
      }
      float4 ov; ov.x = res[0]; ov.y = res[1]; ov.z = res[2]; ov.w = res[3];
      *(float4*)(out + (size_t)t * BCHW_ + base + (size_t)((i0 + r) * 32 + c0)) = ov;
    }
  }
}

// ---------------------- MFMA conv branch (1x1 + 3x3 grouped) + BN3/BN4 + add
// D-tile = 32 oc x 32 px (one image row), v_mfma_f32_32x32x16_f16.
// A = weights (m=oc, lane&31; k=(lane>>5)*8+j), B = spikes from transposed
// LDS tile [18 rows][34 px][32 ic] f16, pixel stride 80 B (16B aligned).
// D layout: col(px)=lane&31, row(oc)=(reg&3)+8*(reg>>2)+4*(lane>>5).
#define XSTR_ 80                 // bytes per pixel slot (32 f16 + 8 pad)
#define YSTR_ (34 * XSTR_)       // 2720
#define SROWS_ 18
__global__ __launch_bounds__(256) void k_conv_mfma(
    const unsigned char* __restrict__ xs, const float* __restrict__ x,
    const float* __restrict__ w1, const float* __restrict__ b1,
    const float* __restrict__ w2, const float* __restrict__ b2,
    const float* __restrict__ bnw, const float* __restrict__ bnb,
    const float* __restrict__ bnm, const float* __restrict__ bnv,
    float* out) {
  __shared__ __align__(16) unsigned char S[SROWS_ * 34 * XSTR_];  // 48960 B
  const int tid = threadIdx.x;
  const int n = blockIdx.x, blk = blockIdx.y, y0 = blockIdx.z * 16;
  const int wv = tid >> 6, ln = tid & 63;
  // zero LDS (covers x/y halo padding)
  for (int i = tid; i < SROWS_ * 34 * XSTR_ / 4; i += 256)
    ((unsigned int*)S)[i] = 0u;
  __syncthreads();
  // ---- stage spikes u8 -> f16, transposed to [row][px][ic] ----
  {
    const int ic4 = ln >> 3, px4 = ln & 7;
    const size_t gb = (size_t)n * CHW_ + (size_t)(blk * 32 + ic4 * 4) * HW_;
    for (int row = wv; row < SROWS_; row += 4) {
      int gy = y0 - 1 + row;
      if (gy < 0 || gy > 31) continue;
      const size_t rb = gb + (size_t)gy * 32 + px4 * 4;
      unsigned int d0 = *(const unsigned int*)(xs + rb);
      unsigned int d1 = *(const unsigned int*)(xs + rb + HW_);
      unsigned int d2 = *(const unsigned int*)(xs + rb + 2 * HW_);
      unsigned int d3 = *(const unsigned int*)(xs + rb + 3 * HW_);
#pragma unroll
      for (int p = 0; p < 4; ++p) {
        unsigned int q = ((d0 >> (8 * p)) & 0xFFu)
                       | (((d1 >> (8 * p)) & 0xFFu) << 8)
                       | (((d2 >> (8 * p)) & 0xFFu) << 16)
                       | (((d3 >> (8 * p)) & 0xFFu) << 24);
        unsigned int lo = ((q & 0xFFu) | ((q & 0xFF00u) << 8)) * 0x3C00u;
        unsigned int hi = (((q >> 16) & 0xFFu) | (((q >> 16) & 0xFF00u) << 8)) * 0x3C00u;
        uint2 wv2; wv2.x = lo; wv2.y = hi;
        *(uint2*)&S[row * YSTR_ + (px4 * 4 + p + 1) * XSTR_ + ic4 * 8] = wv2;
      }
    }
  }
  // ---- per-wave A fragments (f16 weights) + epilogue params ----
  const int oc_a = ln & 31, hh = ln >> 5;
  half8_t A2[18], A1[2];
#pragma unroll
  for (int tap = 0; tap < 9; ++tap) {
#pragma unroll
    for (int kh = 0; kh < 2; ++kh) {
      half8_t a;
#pragma unroll
      for (int j = 0; j < 8; ++j) {
        int ic = kh * 16 + hh * 8 + j;
        a[j] = (_Float16)w2[(oc_a * 32 + ic) * 9 + tap];
      }
      A2[tap * 2 + kh] = a;
    }
  }
#pragma unroll
  for (int kh = 0; kh < 2; ++kh) {
    half8_t a;
#pragma unroll
    for (int j = 0; j < 8; ++j)
      a[j] = (_Float16)w1[oc_a * 32 + kh * 16 + hh * 8 + j];
    A1[kh] = a;
  }
  float p3[16], p4[16], pcc[16];
#pragma unroll
  for (int r = 0; r < 16; ++r) {
    const int oc = (r & 3) + 8 * (r >> 2) + 4 * hh;
    const int c = blk * 32 + oc;
    const float i3 = bnw[3 * C_ + c] / sqrtf(bnv[3 * C_ + c] + EPS_);
    const float e3 = __fsub_rn(bnb[3 * C_ + c], __fmul_rn(bnm[3 * C_ + c], i3));
    const float i4 = bnw[4 * C_ + c] / sqrtf(bnv[4 * C_ + c] + EPS_);
    const float e4 = __fsub_rn(bnb[4 * C_ + c], __fmul_rn(bnm[4 * C_ + c], i4));
    p3[r] = i3; p4[r] = i4;
    pcc[r] = __fadd_rn(__fadd_rn(__fmul_rn(b1[oc], i3), e3),
                       __fadd_rn(__fmul_rn(b2[oc], i4), e4));
  }
  __syncthreads();
  // ---- compute: wave handles 4 row-tiles ----
  const int px = ln & 31;
  for (int i = 0; i < 4; ++i) {
    const int ly = wv * 4 + i;
    f32x16_t ac1, ac2;
#pragma unroll
    for (int r = 0; r < 16; ++r) { ac1[r] = 0.f; ac2[r] = 0.f; }
#pragma unroll
    for (int tap = 0; tap < 9; ++tap) {
      const int dy = tap / 3, dx = tap % 3;
#pragma unroll
      for (int kh = 0; kh < 2; ++kh) {
        half8_t b = *(const half8_t*)&S[(ly + dy) * YSTR_ + (px + dx) * XSTR_
                                        + kh * 32 + hh * 16];
        ac2 = __builtin_amdgcn_mfma_f32_32x32x16_f16(A2[tap * 2 + kh], b, ac2, 0, 0, 0);
        if (tap == 4)
          ac1 = __builtin_amdgcn_mfma_f32_32x32x16_f16(A1[kh], b, ac1, 0, 0, 0);
      }
    }
    // epilogue: out = haar(out) + BN3(conv1) + BN4(conv2) + x
    const int y = y0 + ly;
#pragma unroll
    for (int r = 0; r < 16; ++r) {
      const int oc = (r & 3) + 8 * (r >> 2) + 4 * hh;
      const size_t off = (size_t)n * CHW_ + (size_t)(blk * 32 + oc) * HW_
                       + (size_t)(y * 32 + px);
      const float hv = out[off];
      const float xv = x[off];
      float t1 = __fadd_rn(hv, __fmul_rn(ac1[r], p3[r]));
      float t2 = __fadd_rn(t1, __fmul_rn(ac2[r], p4[r]));
      out[off] = __fadd_rn(__fadd_rn(t2, pcc[r]), xv);
    }
  }
}

extern "C" void kernel_launch(void* const* d_in, const int* in_sizes, int n_in,
                              void* d_out, int out_size, void* d_ws, size_t ws_size,
                              hipStream_t stream) {
  (void)in_sizes; (void)n_in; (void)out_size; (void)ws_size;
  const float* x   = (const float*)d_in[0];
  const float* hwt = (const float*)d_in[1];
  const float* w1  = (const float*)d_in[2];
  const float* b1  = (const float*)d_in[3];
  const float* w2  = (const float*)d_in[4];
  const float* b2  = (const float*)d_in[5];
  const float* bnw = (const float*)d_in[6];
  const float* bnb = (const float*)d_in[7];
  const float* bnm = (const float*)d_in[8];
  const float* bnv = (const float*)d_in[9];
  float* out = (float*)d_out;

  float* qg = (float*)d_ws;
  unsigned char* xs = (unsigned char*)d_ws + 4096;
  unsigned char* h1 = xs + (size_t)T_ * BCHW_;

  k_build_q<<<1, 1024, 0, stream>>>(qg);
  k_lif_x<<<BCHW_ / 1024, 256, 0, stream>>>(x, xs);
  k_haar_fwd<<<(B_ * C_) / 4, 256, 0, stream>>>(xs, qg, bnw, bnb, bnm, bnv, h1);
  k_mix<<<dim3(T_ * B_, NB_), 256, 0, stream>>>(h1, hwt, bnw, bnb, bnm, bnv, out);
  k_haar_inv<<<(B_ * C_) / 4, 256, 0, stream>>>(qg, bnw, bnb, bnm, bnv, out);
  k_conv_mfma<<<dim3(T_ * B_, NB_, 2), 256, 0, stream>>>(xs, x, w1, b1, w2, b2,
                                                         bnw, bnb, bnm, bnv, out);
}